// Round 8
// baseline (841.458 us; speedup 1.0000x reference)
//
#include <hip/hip_runtime.h>

#define N_NODES 20000
#define N_EDGES 640000
#define DIM 128
#define NGRAPH 64
#define NBUCK 313          // ceil(20000/64) dst buckets of 64 nodes
#define EPB 2048           // edges per histogram/partition block
#define NB_HIST 313        // ceil(640000/2048)
#define NB_WCONV 32        // weight conversion blocks

typedef __attribute__((ext_vector_type(8))) short short8;
typedef __attribute__((ext_vector_type(4))) float floatx4;

// round-to-nearest-even fp32 -> bf16 (as uint low 16)
__device__ __forceinline__ unsigned int bf16rne(float f) {
    unsigned int u = __float_as_uint(f);
    return (u + 0x7FFFu + ((u >> 16) & 1u)) >> 16;
}

// ---------------------------------------------------------------------------
// K_front: fused [dst-bucket histogram + last-block scan | weight split-bf16
// convert | params]. (x conversion now lives inside k_gemm.)
// ---------------------------------------------------------------------------
__global__ __launch_bounds__(256) void k_front(
    const int* __restrict__ dst,
    const float* __restrict__ Wrel, const float* __restrict__ Wroot,
    const float* __restrict__ W3rel, const float* __restrict__ W3root,
    const float* __restrict__ b3, const float* __restrict__ Wlin,
    unsigned short* __restrict__ wbh, unsigned short* __restrict__ wbl,
    int* __restrict__ ghist, int* __restrict__ ticket_hist,
    int* __restrict__ boff, int* __restrict__ gcursor,
    float* __restrict__ vrel, float* __restrict__ vroot, float* __restrict__ cb3) {

    const int t = threadIdx.x;
    const int blk = blockIdx.x;

    if (blk < NB_HIST) {
        __shared__ int lhist[NBUCK];
        __shared__ int islast;
        for (int i = t; i < NBUCK; i += 256) lhist[i] = 0;
        __syncthreads();
        const int e0 = blk * EPB;
        for (int i = 0; i < 8; ++i) {
            int e = e0 + i * 256 + t;
            if (e < N_EDGES) atomicAdd(&lhist[dst[e] >> 6], 1);
        }
        __syncthreads();
        for (int i = t; i < NBUCK; i += 256)
            if (lhist[i]) atomicAdd(&ghist[i], lhist[i]);
        __syncthreads();
        if (t == 0) {
            __threadfence();
            islast = (atomicAdd(ticket_hist, 1) == NB_HIST - 1);
        }
        __syncthreads();
        if (islast) {
            __threadfence();
            if (t < 64) {
                int carry = 0;
                for (int c = 0; c < 5; ++c) {
                    int idx = c * 64 + t;
                    int v = (idx < NBUCK)
                        ? __hip_atomic_load(&ghist[idx], __ATOMIC_RELAXED,
                                            __HIP_MEMORY_SCOPE_AGENT)
                        : 0;
                    int xv = v;
                    for (int s = 1; s < 64; s <<= 1) {
                        int u = __shfl_up(xv, s);
                        if (t >= s) xv += u;
                    }
                    int excl = carry + xv - v;
                    if (idx < NBUCK) { boff[idx] = excl; gcursor[idx] = excl; }
                    carry += __shfl(xv, 63);
                }
                if (t == 0) boff[NBUCK] = carry;
            }
        }
    } else if (blk < NB_HIST + NB_WCONV) {
        // weights -> (hi, lo) bf16 split; wb[n][k]: n<128 Wrel, else Wroot
        const int b = blk - NB_HIST;
        for (int i = b * 256 + t; i < 256 * DIM; i += NB_WCONV * 256) {
            int n = i >> 7, k = i & 127;
            float v = (n < DIM) ? Wrel[n * DIM + k] : Wroot[(n - DIM) * DIM + k];
            unsigned int h = bf16rne(v);
            wbh[i] = (unsigned short)h;
            wbl[i] = (unsigned short)bf16rne(v - __uint_as_float(h << 16));
        }
    } else {
        // params: vrel, vroot, cb3
        if (t < 64) {
            for (int kk = 0; kk < 2; ++kk) {
                int k = t + kk * 64;
                float sr = 0.f, so = 0.f;
                for (int h = 0; h < DIM; ++h) {
                    float wl = Wlin[h];
                    sr = fmaf(wl, W3rel[h * DIM + k], sr);
                    so = fmaf(wl, W3root[h * DIM + k], so);
                }
                vrel[k] = sr;
                vroot[k] = so;
            }
            float c = b3[t] * Wlin[t] + b3[t + 64] * Wlin[t + 64];
            for (int m = 32; m > 0; m >>= 1) c += __shfl_xor(c, m);
            if (t == 0) cb3[0] = c;
        }
    }
}

// ---------------------------------------------------------------------------
// K_partition: scatter edges into dst-buckets with LDS reorder so global
// stores are coalesced runs. record.x = (dst<<16)|src (both < 32768).
// ---------------------------------------------------------------------------
__global__ __launch_bounds__(256) void k_partition(const int* __restrict__ src,
                                                   const int* __restrict__ dst,
                                                   const float* __restrict__ ew,
                                                   int* __restrict__ gcursor,
                                                   int2* __restrict__ part) {
    __shared__ int lhist[NBUCK], lbase[NBUCK], gbase[NBUCK], lcur[NBUCK];
    __shared__ int2 lrec[EPB];   // 16 KB
    const int t = threadIdx.x;
    for (int i = t; i < NBUCK; i += 256) lhist[i] = 0;
    __syncthreads();
    const int e0 = blockIdx.x * EPB;
    const int tot = min(EPB, N_EDGES - e0);
    int mys[8], myd[8];
    float myw[8];
    for (int i = 0; i < 8; ++i) {
        int e = e0 + i * 256 + t;
        if (e < N_EDGES) {
            mys[i] = src[e];
            myd[i] = dst[e];
            myw[i] = ew[e];
            atomicAdd(&lhist[myd[i] >> 6], 1);
        } else {
            myd[i] = -1;
        }
    }
    __syncthreads();
    // local exclusive scan (one wave)
    if (t < 64) {
        int carry = 0;
        for (int c = 0; c < 5; ++c) {
            int idx = c * 64 + t;
            int v = (idx < NBUCK) ? lhist[idx] : 0;
            int xv = v;
            for (int s = 1; s < 64; s <<= 1) {
                int u = __shfl_up(xv, s);
                if (t >= s) xv += u;
            }
            if (idx < NBUCK) { lbase[idx] = carry + xv - v; lcur[idx] = 0; }
            carry += __shfl(xv, 63);
        }
    }
    __syncthreads();
    // reserve global ranges
    for (int i = t; i < NBUCK; i += 256) {
        int cnt = lhist[i];
        gbase[i] = cnt ? atomicAdd(&gcursor[i], cnt) : 0;
    }
    __syncthreads();
    // scatter into LDS (bucket-sorted)
    for (int i = 0; i < 8; ++i) {
        if (myd[i] >= 0) {
            int bb = myd[i] >> 6;
            int slot = lbase[bb] + atomicAdd(&lcur[bb], 1);
            lrec[slot] = make_int2((myd[i] << 16) | mys[i], __float_as_int(myw[i]));
        }
    }
    __syncthreads();
    // coalesced write-out
    for (int i = t; i < tot; i += 256) {
        int2 rc = lrec[i];
        int bb = (rc.x >> 16) >> 6;
        part[gbase[bb] + (i - lbase[bb])] = rc;
    }
}

// ---------------------------------------------------------------------------
// K_gemm: split-bf16 MFMA GEMM; x converted hi/lo in-register; weights from
// LDS (XOR-swizzled, as r7). grid = (313 row-tiles, 2 col-halves).
// D = Ah*Bh + Al*Bh + Ah*Bl.
// ---------------------------------------------------------------------------
__global__ __launch_bounds__(256) void k_gemm(
    const float* __restrict__ x,
    const unsigned short* __restrict__ wbh, const unsigned short* __restrict__ wbl,
    const float* __restrict__ b1,
    unsigned short* __restrict__ yb, float* __restrict__ r) {
    extern __shared__ unsigned short smem[];   // [0,32KB) hi, [32KB,64KB) lo
    uint4* sh = (uint4*)smem;
    uint4* sl = (uint4*)(smem + 16384);

    const int t = threadIdx.x;
    const int g = blockIdx.x;
    const int half = blockIdx.y;
    const int n0 = half * 128;

    const uint4* gh = (const uint4*)wbh + (size_t)n0 * 16;
    const uint4* gl = (const uint4*)wbl + (size_t)n0 * 16;
    for (int i = t; i < 2048; i += 256) {
        int row = i >> 4, c = i & 15;
        int sc = row * 16 + (c ^ (row & 15));
        sh[sc] = gh[i];
        sl[sc] = gl[i];
    }
    __syncthreads();

    const int lane = t & 63;
    const int m = lane & 15;
    const int q = lane >> 4;
    const int row0 = g * 64 + (t >> 6) * 16;
    const int row = row0 + m;
    const bool ok = row < N_NODES;

    const short8* SH = (const short8*)smem;
    const short8* SL = (const short8*)(smem + 16384);

    floatx4 acc[8];
    #pragma unroll
    for (int i = 0; i < 8; ++i) acc[i] = (floatx4)(0.f);

    #pragma unroll
    for (int kc = 0; kc < 4; ++kc) {
        float4 v0 = make_float4(0.f, 0.f, 0.f, 0.f);
        float4 v1 = make_float4(0.f, 0.f, 0.f, 0.f);
        if (ok) {
            const float4* xp = (const float4*)(x + (size_t)row * DIM + kc * 32 + q * 8);
            v0 = xp[0];
            v1 = xp[1];
        }
        float f[8] = {v0.x, v0.y, v0.z, v0.w, v1.x, v1.y, v1.z, v1.w};
        short8 ah, al;
        #pragma unroll
        for (int i = 0; i < 8; ++i) {
            unsigned int h = bf16rne(f[i]);
            ah[i] = (short)h;
            al[i] = (short)bf16rne(f[i] - __uint_as_float(h << 16));
        }
        #pragma unroll
        for (int nt = 0; nt < 8; ++nt) {
            int n = nt * 16 + m;
            int cc = (kc * 4 + q) ^ m;
            short8 bh = SH[n * 16 + cc];
            short8 bl = SL[n * 16 + cc];
            acc[nt] = __builtin_amdgcn_mfma_f32_16x16x32_bf16(ah, bh, acc[nt], 0, 0, 0);
            acc[nt] = __builtin_amdgcn_mfma_f32_16x16x32_bf16(al, bh, acc[nt], 0, 0, 0);
            acc[nt] = __builtin_amdgcn_mfma_f32_16x16x32_bf16(ah, bl, acc[nt], 0, 0, 0);
        }
    }

    // epilogue: C/D layout col=lane&15, row=q*4+reg
    #pragma unroll
    for (int nt = 0; nt < 8; ++nt) {
        int col = n0 + nt * 16 + m;
        float bias = (col >= DIM) ? b1[col - DIM] : 0.f;
        #pragma unroll
        for (int reg = 0; reg < 4; ++reg) {
            int orow = row0 + q * 4 + reg;
            if (orow < N_NODES) {
                float v = acc[nt][reg];
                if (col < DIM)
                    yb[orow * DIM + col] = (unsigned short)bf16rne(v);
                else
                    r[orow * DIM + (col - DIM)] = v + bias;
            }
        }
    }
}

// ---------------------------------------------------------------------------
// K_agg: block per bucket; LDS acc[64][128]; scatter-accumulate unsorted part
// records via ds_add_f32 (parity-staggered → 2-way bank aliasing, free);
// then h1 = relu(acc + r), a = h1.vrel, b = h1.vroot per node.
// ---------------------------------------------------------------------------
__global__ __launch_bounds__(256) void k_agg(const unsigned int* __restrict__ yb,
                                             const float2* __restrict__ r2,
                                             const int* __restrict__ boff,
                                             const int2* __restrict__ part,
                                             const float2* __restrict__ vrel2,
                                             const float2* __restrict__ vroot2,
                                             float* __restrict__ aout,
                                             float* __restrict__ bout) {
    __shared__ float acc[64 * DIM];   // 32 KB
    const int t = threadIdx.x;
    const int b = blockIdx.x;
    for (int i = t; i < 64 * DIM; i += 256) acc[i] = 0.f;
    __syncthreads();

    const int lane = t & 63;
    const int w = t >> 6;
    const int s0 = boff[b], s1 = boff[b + 1];
    const int cnt = s1 - s0;
    const int chunk = (cnt + 3) >> 2;
    int j = s0 + w * chunk;
    const int jend = min(j + chunk, s1);
    const int p = lane & 1;

    for (; j + 4 <= jend; j += 4) {
        int2 r0 = part[j], r1 = part[j + 1], r2_ = part[j + 2], r3 = part[j + 3];
        float w0 = __int_as_float(r0.y), w1 = __int_as_float(r1.y);
        float w2 = __int_as_float(r2_.y), w3 = __int_as_float(r3.y);
        unsigned int v0 = yb[(r0.x & 0xFFFF) * 64 + lane];
        unsigned int v1 = yb[(r1.x & 0xFFFF) * 64 + lane];
        unsigned int v2 = yb[(r2_.x & 0xFFFF) * 64 + lane];
        unsigned int v3 = yb[(r3.x & 0xFFFF) * 64 + lane];
        int b0 = ((r0.x >> 16) & 63) * DIM + 2 * lane;
        int b1_ = ((r1.x >> 16) & 63) * DIM + 2 * lane;
        int b2 = ((r2_.x >> 16) & 63) * DIM + 2 * lane;
        int b3_ = ((r3.x >> 16) & 63) * DIM + 2 * lane;
        float lo0 = __uint_as_float(v0 << 16) * w0, hi0 = __uint_as_float(v0 & 0xFFFF0000u) * w0;
        float lo1 = __uint_as_float(v1 << 16) * w1, hi1 = __uint_as_float(v1 & 0xFFFF0000u) * w1;
        float lo2 = __uint_as_float(v2 << 16) * w2, hi2 = __uint_as_float(v2 & 0xFFFF0000u) * w2;
        float lo3 = __uint_as_float(v3 << 16) * w3, hi3 = __uint_as_float(v3 & 0xFFFF0000u) * w3;
        atomicAdd(&acc[b0 + p], p ? hi0 : lo0);
        atomicAdd(&acc[b0 + 1 - p], p ? lo0 : hi0);
        atomicAdd(&acc[b1_ + p], p ? hi1 : lo1);
        atomicAdd(&acc[b1_ + 1 - p], p ? lo1 : hi1);
        atomicAdd(&acc[b2 + p], p ? hi2 : lo2);
        atomicAdd(&acc[b2 + 1 - p], p ? lo2 : hi2);
        atomicAdd(&acc[b3_ + p], p ? hi3 : lo3);
        atomicAdd(&acc[b3_ + 1 - p], p ? lo3 : hi3);
    }
    for (; j < jend; ++j) {
        int2 rc = part[j];
        float wt = __int_as_float(rc.y);
        unsigned int v = yb[(rc.x & 0xFFFF) * 64 + lane];
        int ba = ((rc.x >> 16) & 63) * DIM + 2 * lane;
        float lo = __uint_as_float(v << 16) * wt, hi = __uint_as_float(v & 0xFFFF0000u) * wt;
        atomicAdd(&acc[ba + p], p ? hi : lo);
        atomicAdd(&acc[ba + 1 - p], p ? lo : hi);
    }
    __syncthreads();

    float2 vr = vrel2[lane];
    float2 vo = vroot2[lane];
    for (int n = w; n < 64; n += 4) {
        int node = b * 64 + n;
        if (node >= N_NODES) break;
        float ax = acc[n * DIM + 2 * lane];
        float ay = acc[n * DIM + 2 * lane + 1];
        float2 rr = r2[(size_t)node * 64 + lane];
        float hx = fmaxf(ax + rr.x, 0.f);
        float hy = fmaxf(ay + rr.y, 0.f);
        float pa = hx * vr.x + hy * vr.y;
        float pb = hx * vo.x + hy * vo.y;
        for (int mm = 32; mm > 0; mm >>= 1) {
            pa += __shfl_xor(pa, mm);
            pb += __shfl_xor(pb, mm);
        }
        if (lane == 0) {
            aout[node] = pa;
            bout[node] = pb;
        }
    }
}

// ---------------------------------------------------------------------------
// K_reduce: block per bucket; s[dl] += w*a[src] (LDS); bin nodes by graph;
// spread partials; last block computes out[].
// ---------------------------------------------------------------------------
__global__ __launch_bounds__(256) void k_reduce(
    const int2* __restrict__ part, const int* __restrict__ boff,
    const float* __restrict__ a, const float* __restrict__ bvec,
    const int* __restrict__ batch,
    float* __restrict__ gpart, int* __restrict__ gpartc,
    int* __restrict__ ticket_red,
    const float* __restrict__ cb3, const float* __restrict__ blin,
    float* __restrict__ out) {
    __shared__ float s[64];
    __shared__ float sbin[NGRAPH];
    __shared__ int cbin[NGRAPH];
    __shared__ int islast;
    const int t = threadIdx.x;
    if (t < 64) s[t] = 0.f;
    for (int i = t; i < NGRAPH; i += 256) { sbin[i] = 0.f; cbin[i] = 0; }
    __syncthreads();
    const int b = blockIdx.x;
    const int s0 = boff[b], s1 = boff[b + 1];
    for (int i = s0 + t; i < s1; i += 256) {
        int2 rc = part[i];
        atomicAdd(&s[(rc.x >> 16) & 63], __int_as_float(rc.y) * a[rc.x & 0xFFFF]);
    }
    __syncthreads();
    if (t < 64) {
        int node = b * 64 + t;
        if (node < N_NODES) {
            float val = s[t] + bvec[node];
            int g = batch[node];
            atomicAdd(&sbin[g], val);
            atomicAdd(&cbin[g], 1);
        }
    }
    __syncthreads();
    const int slot = b & 63;
    for (int i = t; i < NGRAPH; i += 256) {
        if (sbin[i] != 0.f) atomicAdd(&gpart[slot * NGRAPH + i], sbin[i]);
        if (cbin[i]) atomicAdd(&gpartc[slot * NGRAPH + i], cbin[i]);
    }
    __syncthreads();
    if (t == 0) {
        __threadfence();
        islast = (atomicAdd(ticket_red, 1) == (int)gridDim.x - 1);
    }
    __syncthreads();
    if (islast) {
        __threadfence();
        if (t < NGRAPH) {
            float S = 0.f;
            int C = 0;
            for (int s2 = 0; s2 < 64; ++s2) {
                S += __hip_atomic_load(&gpart[s2 * NGRAPH + t], __ATOMIC_RELAXED,
                                       __HIP_MEMORY_SCOPE_AGENT);
                C += __hip_atomic_load(&gpartc[s2 * NGRAPH + t], __ATOMIC_RELAXED,
                                       __HIP_MEMORY_SCOPE_AGENT);
            }
            float denom = (C > 0) ? (float)C : 1.f;
            float v = (S + (float)C * cb3[0]) / denom + blin[0];
            out[t] = (v > 0.f) ? v : 0.f;
        }
    }
}

// ---------------------------------------------------------------------------
extern "C" void kernel_launch(void* const* d_in, const int* in_sizes, int n_in,
                              void* d_out, int out_size, void* d_ws, size_t ws_size,
                              hipStream_t stream) {
    const float* x = (const float*)d_in[0];
    const int* edge_index = (const int*)d_in[1];
    const int* src = edge_index;
    const int* dst = edge_index + N_EDGES;
    const int* batch = (const int*)d_in[2];
    const float* ew = (const float*)d_in[3];
    const float* W1rel = (const float*)d_in[4];
    const float* b1 = (const float*)d_in[5];
    const float* W1root = (const float*)d_in[6];
    const float* W3rel = (const float*)d_in[7];
    const float* b3 = (const float*)d_in[8];
    const float* W3root = (const float*)d_in[9];
    const float* Wlin = (const float*)d_in[10];
    const float* blin = (const float*)d_in[11];
    float* out = (float*)d_out;

    char* w = (char*)d_ws;
    size_t o = 0;
    auto alloc = [&](size_t bytes) -> void* {
        void* p = w + o;
        o += bytes;
        o = (o + 255) & ~(size_t)255;
        return p;
    };
    char* zbase = (char*)alloc(1280 + 64 * NGRAPH * 4 * 2);
    int* ghist = (int*)zbase;
    int* ticket_hist = ghist + NBUCK;
    int* ticket_red = ghist + NBUCK + 1;
    float* gpart = (float*)(zbase + 1280);
    int* gpartc = (int*)(zbase + 1280 + 64 * NGRAPH * 4);
    const size_t zbytes = 1280 + 64 * NGRAPH * 4 * 2;

    unsigned short* wbh = (unsigned short*)alloc((size_t)256 * DIM * 2);
    unsigned short* wbl = (unsigned short*)alloc((size_t)256 * DIM * 2);
    unsigned short* yb = (unsigned short*)alloc((size_t)N_NODES * DIM * 2);  // bf16
    float* r = (float*)alloc((size_t)N_NODES * DIM * 4);
    int* boff = (int*)alloc((size_t)(NBUCK + 1) * 4);
    int* gcursor = (int*)alloc((size_t)NBUCK * 4);
    int2* part = (int2*)alloc((size_t)N_EDGES * 8);
    float* a = (float*)alloc((size_t)N_NODES * 4);
    float* b = (float*)alloc((size_t)N_NODES * 4);
    float* vrel = (float*)alloc(DIM * 4);
    float* vroot = (float*)alloc(DIM * 4);
    float* cb3 = (float*)alloc(4);

    hipMemsetAsync(zbase, 0, zbytes, stream);

    k_front<<<NB_HIST + NB_WCONV + 1, 256, 0, stream>>>(
        dst, W1rel, W1root, W3rel, W3root, b3, Wlin,
        wbh, wbl, ghist, ticket_hist, boff, gcursor, vrel, vroot, cb3);

    k_partition<<<NB_HIST, 256, 0, stream>>>(src, dst, ew, gcursor, part);

    k_gemm<<<dim3(NBUCK, 2), 256, 65536, stream>>>(x, wbh, wbl, b1, yb, r);

    k_agg<<<NBUCK, 256, 0, stream>>>(
        (const unsigned int*)yb, (const float2*)r, boff, part,
        (const float2*)vrel, (const float2*)vroot, a, b);

    k_reduce<<<NBUCK, 256, 0, stream>>>(
        part, boff, a, b, batch, gpart, gpartc, ticket_red, cb3, blin, out);
}

// Round 9
// 194.356 us; speedup vs baseline: 4.3295x; 4.3295x over previous
//
#include <hip/hip_runtime.h>

#define N_NODES 20000
#define N_EDGES 640000
#define DIM 128
#define NGRAPH 64
#define NBUCK 313          // ceil(20000/64) dst buckets of 64 nodes
#define EPB 2048           // edges per histogram/partition block
#define NB_HIST 313        // ceil(640000/2048)
#define NB_WCONV 32        // weight conversion blocks
#define RED_BLOCKS 512

typedef __attribute__((ext_vector_type(8))) short short8;
typedef __attribute__((ext_vector_type(4))) float floatx4;

// round-to-nearest-even fp32 -> bf16 (as uint low 16)
__device__ __forceinline__ unsigned int bf16rne(float f) {
    unsigned int u = __float_as_uint(f);
    return (u + 0x7FFFu + ((u >> 16) & 1u)) >> 16;
}

// ---------------------------------------------------------------------------
// K_front: fused [dst-bucket histogram + last-block scan | weight split-bf16
// convert | params].
// ---------------------------------------------------------------------------
__global__ __launch_bounds__(256) void k_front(
    const int* __restrict__ dst,
    const float* __restrict__ Wrel, const float* __restrict__ Wroot,
    const float* __restrict__ W3rel, const float* __restrict__ W3root,
    const float* __restrict__ b3, const float* __restrict__ Wlin,
    unsigned short* __restrict__ wbh, unsigned short* __restrict__ wbl,
    int* __restrict__ ghist, int* __restrict__ ticket_hist,
    int* __restrict__ boff, int* __restrict__ gcursor,
    float* __restrict__ vrel, float* __restrict__ vroot, float* __restrict__ cb3) {

    const int t = threadIdx.x;
    const int blk = blockIdx.x;

    if (blk < NB_HIST) {
        __shared__ int lhist[NBUCK];
        __shared__ int islast;
        for (int i = t; i < NBUCK; i += 256) lhist[i] = 0;
        __syncthreads();
        const int e0 = blk * EPB;
        for (int i = 0; i < 8; ++i) {
            int e = e0 + i * 256 + t;
            if (e < N_EDGES) atomicAdd(&lhist[dst[e] >> 6], 1);
        }
        __syncthreads();
        for (int i = t; i < NBUCK; i += 256)
            if (lhist[i]) atomicAdd(&ghist[i], lhist[i]);
        __syncthreads();
        if (t == 0) {
            __threadfence();
            islast = (atomicAdd(ticket_hist, 1) == NB_HIST - 1);
        }
        __syncthreads();
        if (islast) {
            __threadfence();
            if (t < 64) {
                int carry = 0;
                for (int c = 0; c < 5; ++c) {
                    int idx = c * 64 + t;
                    int v = (idx < NBUCK)
                        ? __hip_atomic_load(&ghist[idx], __ATOMIC_RELAXED,
                                            __HIP_MEMORY_SCOPE_AGENT)
                        : 0;
                    int xv = v;
                    for (int s = 1; s < 64; s <<= 1) {
                        int u = __shfl_up(xv, s);
                        if (t >= s) xv += u;
                    }
                    int excl = carry + xv - v;
                    if (idx < NBUCK) { boff[idx] = excl; gcursor[idx] = excl; }
                    carry += __shfl(xv, 63);
                }
                if (t == 0) boff[NBUCK] = carry;
            }
        }
    } else if (blk < NB_HIST + NB_WCONV) {
        const int b = blk - NB_HIST;
        for (int i = b * 256 + t; i < 256 * DIM; i += NB_WCONV * 256) {
            int n = i >> 7, k = i & 127;
            float v = (n < DIM) ? Wrel[n * DIM + k] : Wroot[(n - DIM) * DIM + k];
            unsigned int h = bf16rne(v);
            wbh[i] = (unsigned short)h;
            wbl[i] = (unsigned short)bf16rne(v - __uint_as_float(h << 16));
        }
    } else {
        if (t < 64) {
            for (int kk = 0; kk < 2; ++kk) {
                int k = t + kk * 64;
                float sr = 0.f, so = 0.f;
                for (int h = 0; h < DIM; ++h) {
                    float wl = Wlin[h];
                    sr = fmaf(wl, W3rel[h * DIM + k], sr);
                    so = fmaf(wl, W3root[h * DIM + k], so);
                }
                vrel[k] = sr;
                vroot[k] = so;
            }
            float c = b3[t] * Wlin[t] + b3[t + 64] * Wlin[t + 64];
            for (int m = 32; m > 0; m >>= 1) c += __shfl_xor(c, m);
            if (t == 0) cb3[0] = c;
        }
    }
}

// ---------------------------------------------------------------------------
// K_partition: scatter edges into dst-buckets with LDS reorder so global
// stores are coalesced runs. record.x = (dst<<16)|src (both < 32768).
// ---------------------------------------------------------------------------
__global__ __launch_bounds__(256) void k_partition(const int* __restrict__ src,
                                                   const int* __restrict__ dst,
                                                   const float* __restrict__ ew,
                                                   int* __restrict__ gcursor,
                                                   int2* __restrict__ part) {
    __shared__ int lhist[NBUCK], lbase[NBUCK], gbase[NBUCK], lcur[NBUCK];
    __shared__ int2 lrec[EPB];   // 16 KB
    const int t = threadIdx.x;
    for (int i = t; i < NBUCK; i += 256) lhist[i] = 0;
    __syncthreads();
    const int e0 = blockIdx.x * EPB;
    const int tot = min(EPB, N_EDGES - e0);
    int mys[8], myd[8];
    float myw[8];
    for (int i = 0; i < 8; ++i) {
        int e = e0 + i * 256 + t;
        if (e < N_EDGES) {
            mys[i] = src[e];
            myd[i] = dst[e];
            myw[i] = ew[e];
            atomicAdd(&lhist[myd[i] >> 6], 1);
        } else {
            myd[i] = -1;
        }
    }
    __syncthreads();
    if (t < 64) {
        int carry = 0;
        for (int c = 0; c < 5; ++c) {
            int idx = c * 64 + t;
            int v = (idx < NBUCK) ? lhist[idx] : 0;
            int xv = v;
            for (int s = 1; s < 64; s <<= 1) {
                int u = __shfl_up(xv, s);
                if (t >= s) xv += u;
            }
            if (idx < NBUCK) { lbase[idx] = carry + xv - v; lcur[idx] = 0; }
            carry += __shfl(xv, 63);
        }
    }
    __syncthreads();
    for (int i = t; i < NBUCK; i += 256) {
        int cnt = lhist[i];
        gbase[i] = cnt ? atomicAdd(&gcursor[i], cnt) : 0;
    }
    __syncthreads();
    for (int i = 0; i < 8; ++i) {
        if (myd[i] >= 0) {
            int bb = myd[i] >> 6;
            int slot = lbase[bb] + atomicAdd(&lcur[bb], 1);
            lrec[slot] = make_int2((myd[i] << 16) | mys[i], __float_as_int(myw[i]));
        }
    }
    __syncthreads();
    for (int i = t; i < tot; i += 256) {
        int2 rc = lrec[i];
        int bb = (rc.x >> 16) >> 6;
        part[gbase[bb] + (i - lbase[bb])] = rc;
    }
}

// ---------------------------------------------------------------------------
// K_gemm: split-bf16 MFMA GEMM; x converted hi/lo in-register; weights from
// LDS (XOR-swizzled). grid = (313 row-tiles, 2 col-halves).
// D = Ah*Bh + Al*Bh + Ah*Bl.
// ---------------------------------------------------------------------------
__global__ __launch_bounds__(256) void k_gemm(
    const float* __restrict__ x,
    const unsigned short* __restrict__ wbh, const unsigned short* __restrict__ wbl,
    const float* __restrict__ b1,
    unsigned short* __restrict__ yb, float* __restrict__ r) {
    extern __shared__ unsigned short smem[];   // [0,32KB) hi, [32KB,64KB) lo
    uint4* sh = (uint4*)smem;
    uint4* sl = (uint4*)(smem + 16384);

    const int t = threadIdx.x;
    const int g = blockIdx.x;
    const int half = blockIdx.y;
    const int n0 = half * 128;

    const uint4* gh = (const uint4*)wbh + (size_t)n0 * 16;
    const uint4* gl = (const uint4*)wbl + (size_t)n0 * 16;
    for (int i = t; i < 2048; i += 256) {
        int row = i >> 4, c = i & 15;
        int sc = row * 16 + (c ^ (row & 15));
        sh[sc] = gh[i];
        sl[sc] = gl[i];
    }
    __syncthreads();

    const int lane = t & 63;
    const int m = lane & 15;
    const int q = lane >> 4;
    const int row0 = g * 64 + (t >> 6) * 16;
    const int row = row0 + m;
    const bool ok = row < N_NODES;

    const short8* SH = (const short8*)smem;
    const short8* SL = (const short8*)(smem + 16384);

    floatx4 acc[8];
    #pragma unroll
    for (int i = 0; i < 8; ++i) acc[i] = (floatx4)(0.f);

    #pragma unroll
    for (int kc = 0; kc < 4; ++kc) {
        float4 v0 = make_float4(0.f, 0.f, 0.f, 0.f);
        float4 v1 = make_float4(0.f, 0.f, 0.f, 0.f);
        if (ok) {
            const float4* xp = (const float4*)(x + (size_t)row * DIM + kc * 32 + q * 8);
            v0 = xp[0];
            v1 = xp[1];
        }
        float f[8] = {v0.x, v0.y, v0.z, v0.w, v1.x, v1.y, v1.z, v1.w};
        short8 ah, al;
        #pragma unroll
        for (int i = 0; i < 8; ++i) {
            unsigned int h = bf16rne(f[i]);
            ah[i] = (short)h;
            al[i] = (short)bf16rne(f[i] - __uint_as_float(h << 16));
        }
        #pragma unroll
        for (int nt = 0; nt < 8; ++nt) {
            int n = nt * 16 + m;
            int cc = (kc * 4 + q) ^ m;
            short8 bh = SH[n * 16 + cc];
            short8 bl = SL[n * 16 + cc];
            acc[nt] = __builtin_amdgcn_mfma_f32_16x16x32_bf16(ah, bh, acc[nt], 0, 0, 0);
            acc[nt] = __builtin_amdgcn_mfma_f32_16x16x32_bf16(al, bh, acc[nt], 0, 0, 0);
            acc[nt] = __builtin_amdgcn_mfma_f32_16x16x32_bf16(ah, bl, acc[nt], 0, 0, 0);
        }
    }

    // epilogue: C/D layout col=lane&15, row=q*4+reg
    #pragma unroll
    for (int nt = 0; nt < 8; ++nt) {
        int col = n0 + nt * 16 + m;
        float bias = (col >= DIM) ? b1[col - DIM] : 0.f;
        #pragma unroll
        for (int reg = 0; reg < 4; ++reg) {
            int orow = row0 + q * 4 + reg;
            if (orow < N_NODES) {
                float v = acc[nt][reg];
                if (col < DIM)
                    yb[orow * DIM + col] = (unsigned short)bf16rne(v);
                else
                    r[orow * DIM + (col - DIM)] = v + bias;
            }
        }
    }
}

// ---------------------------------------------------------------------------
// K_bucketsort: within each bucket, counting-sort records by node; emit CSR off
// sorted.x = src, sorted.y = bits(w)
// ---------------------------------------------------------------------------
__global__ __launch_bounds__(256) void k_bucketsort(const int* __restrict__ boff,
                                                    const int2* __restrict__ part,
                                                    int2* __restrict__ sorted,
                                                    int* __restrict__ off) {
    __shared__ int nh[64], ncur[64];
    const int b = blockIdx.x;
    const int t = threadIdx.x;
    const int s0 = boff[b], s1 = boff[b + 1];
    if (t < 64) nh[t] = 0;
    __syncthreads();
    for (int i = s0 + t; i < s1; i += 256) atomicAdd(&nh[(part[i].x >> 16) & 63], 1);
    __syncthreads();
    if (t < 64) {
        int v = nh[t];
        int xv = v;
        for (int s = 1; s < 64; s <<= 1) {
            int u = __shfl_up(xv, s);
            if (t >= s) xv += u;
        }
        int excl = xv - v;
        ncur[t] = excl;
        int node = b * 64 + t;
        if (node < N_NODES) off[node] = s0 + excl;
    }
    __syncthreads();
    for (int i = s0 + t; i < s1; i += 256) {
        int2 rc = part[i];
        int dl = (rc.x >> 16) & 63;
        int p = atomicAdd(&ncur[dl], 1);
        sorted[s0 + p] = make_int2(rc.x & 0xFFFF, rc.y);
    }
    if (b == 0 && t == 0) off[N_NODES] = N_EDGES;
}

// ---------------------------------------------------------------------------
// K_agg: wave per node; gather bf16 y rows; h1=relu(agg+r); a=h.vrel, b=h.vroot
// ---------------------------------------------------------------------------
__global__ __launch_bounds__(256) void k_agg(const unsigned int* __restrict__ yb,
                                             const float2* __restrict__ r2,
                                             const int* __restrict__ off,
                                             const int2* __restrict__ grec,
                                             const float2* __restrict__ vrel2,
                                             const float2* __restrict__ vroot2,
                                             float* __restrict__ aout,
                                             float* __restrict__ bout) {
    const int lane = threadIdx.x & 63;
    const int node = blockIdx.x * 4 + (threadIdx.x >> 6);
    if (node >= N_NODES) return;

    int j = off[node];
    const int e1 = off[node + 1];
    float sx = 0.f, sy = 0.f;
    for (; j + 4 <= e1; j += 4) {
        int2 r0 = grec[j], r1 = grec[j + 1], rr2 = grec[j + 2], r3 = grec[j + 3];
        float w0 = __int_as_float(r0.y), w1 = __int_as_float(r1.y);
        float w2 = __int_as_float(rr2.y), w3 = __int_as_float(r3.y);
        unsigned int v0 = yb[r0.x * 64 + lane];
        unsigned int v1 = yb[r1.x * 64 + lane];
        unsigned int v2 = yb[rr2.x * 64 + lane];
        unsigned int v3 = yb[r3.x * 64 + lane];
        sx = fmaf(w0, __uint_as_float(v0 << 16),
             fmaf(w1, __uint_as_float(v1 << 16),
             fmaf(w2, __uint_as_float(v2 << 16),
             fmaf(w3, __uint_as_float(v3 << 16), sx))));
        sy = fmaf(w0, __uint_as_float(v0 & 0xFFFF0000u),
             fmaf(w1, __uint_as_float(v1 & 0xFFFF0000u),
             fmaf(w2, __uint_as_float(v2 & 0xFFFF0000u),
             fmaf(w3, __uint_as_float(v3 & 0xFFFF0000u), sy))));
    }
    for (; j < e1; ++j) {
        int2 rc = grec[j];
        float w = __int_as_float(rc.y);
        unsigned int v = yb[rc.x * 64 + lane];
        sx = fmaf(w, __uint_as_float(v << 16), sx);
        sy = fmaf(w, __uint_as_float(v & 0xFFFF0000u), sy);
    }
    float2 rr = r2[(size_t)node * 64 + lane];
    float hx = fmaxf(sx + rr.x, 0.f);
    float hy = fmaxf(sy + rr.y, 0.f);
    float2 vr = vrel2[lane];
    float2 vo = vroot2[lane];
    float pa = hx * vr.x + hy * vr.y;
    float pb = hx * vo.x + hy * vo.y;
    for (int mm = 32; mm > 0; mm >>= 1) {
        pa += __shfl_xor(pa, mm);
        pb += __shfl_xor(pb, mm);
    }
    if (lane == 0) {
        aout[node] = pa;
        bout[node] = pb;
    }
}

// ---------------------------------------------------------------------------
// K_reduce_final: wave per node; bin by graph; spread partials; last block -> out
// ---------------------------------------------------------------------------
__global__ __launch_bounds__(256) void k_reduce_final(
    const int2* __restrict__ sorted, const int* __restrict__ off,
    const float* __restrict__ a, const float* __restrict__ bvec,
    const int* __restrict__ batch,
    float* __restrict__ gpart, int* __restrict__ gpartc,
    int* __restrict__ ticket_red,
    const float* __restrict__ cb3, const float* __restrict__ blin,
    float* __restrict__ out) {
    __shared__ float sbin[NGRAPH];
    __shared__ int cbin[NGRAPH];
    __shared__ int islast;
    const int t = threadIdx.x;
    for (int i = t; i < NGRAPH; i += 256) { sbin[i] = 0.f; cbin[i] = 0; }
    __syncthreads();
    const int lane = t & 63;
    const int gw = blockIdx.x * 4 + (t >> 6);
    const int nw = gridDim.x * 4;
    for (int node = gw; node < N_NODES; node += nw) {
        const int e0 = off[node], e1 = off[node + 1];
        float s = 0.f;
        for (int j = e0 + lane; j < e1; j += 64) {
            int2 rc = sorted[j];
            s = fmaf(__int_as_float(rc.y), a[rc.x], s);
        }
        for (int mm = 32; mm > 0; mm >>= 1) s += __shfl_xor(s, mm);
        if (lane == 0) {
            int g = batch[node];
            atomicAdd(&sbin[g], s + bvec[node]);
            atomicAdd(&cbin[g], 1);
        }
    }
    __syncthreads();
    const int slot = blockIdx.x & 63;
    for (int i = t; i < NGRAPH; i += 256) {
        atomicAdd(&gpart[slot * NGRAPH + i], sbin[i]);
        if (cbin[i]) atomicAdd(&gpartc[slot * NGRAPH + i], cbin[i]);
    }
    __syncthreads();
    if (t == 0) {
        __threadfence();
        islast = (atomicAdd(ticket_red, 1) == (int)gridDim.x - 1);
    }
    __syncthreads();
    if (islast) {
        __threadfence();
        if (t < NGRAPH) {
            float S = 0.f;
            int C = 0;
            for (int s2 = 0; s2 < 64; ++s2) {
                S += __hip_atomic_load(&gpart[s2 * NGRAPH + t], __ATOMIC_RELAXED,
                                       __HIP_MEMORY_SCOPE_AGENT);
                C += __hip_atomic_load(&gpartc[s2 * NGRAPH + t], __ATOMIC_RELAXED,
                                       __HIP_MEMORY_SCOPE_AGENT);
            }
            float denom = (C > 0) ? (float)C : 1.f;
            float v = (S + (float)C * cb3[0]) / denom + blin[0];
            out[t] = (v > 0.f) ? v : 0.f;
        }
    }
}

// ---------------------------------------------------------------------------
extern "C" void kernel_launch(void* const* d_in, const int* in_sizes, int n_in,
                              void* d_out, int out_size, void* d_ws, size_t ws_size,
                              hipStream_t stream) {
    const float* x = (const float*)d_in[0];
    const int* edge_index = (const int*)d_in[1];
    const int* src = edge_index;
    const int* dst = edge_index + N_EDGES;
    const int* batch = (const int*)d_in[2];
    const float* ew = (const float*)d_in[3];
    const float* W1rel = (const float*)d_in[4];
    const float* b1 = (const float*)d_in[5];
    const float* W1root = (const float*)d_in[6];
    const float* W3rel = (const float*)d_in[7];
    const float* b3 = (const float*)d_in[8];
    const float* W3root = (const float*)d_in[9];
    const float* Wlin = (const float*)d_in[10];
    const float* blin = (const float*)d_in[11];
    float* out = (float*)d_out;

    char* w = (char*)d_ws;
    size_t o = 0;
    auto alloc = [&](size_t bytes) -> void* {
        void* p = w + o;
        o += bytes;
        o = (o + 255) & ~(size_t)255;
        return p;
    };
    char* zbase = (char*)alloc(1280 + 64 * NGRAPH * 4 * 2);
    int* ghist = (int*)zbase;
    int* ticket_hist = ghist + NBUCK;
    int* ticket_red = ghist + NBUCK + 1;
    float* gpart = (float*)(zbase + 1280);
    int* gpartc = (int*)(zbase + 1280 + 64 * NGRAPH * 4);
    const size_t zbytes = 1280 + 64 * NGRAPH * 4 * 2;

    unsigned short* wbh = (unsigned short*)alloc((size_t)256 * DIM * 2);
    unsigned short* wbl = (unsigned short*)alloc((size_t)256 * DIM * 2);
    unsigned short* yb = (unsigned short*)alloc((size_t)N_NODES * DIM * 2);  // bf16
    float* r = (float*)alloc((size_t)N_NODES * DIM * 4);
    int* boff = (int*)alloc((size_t)(NBUCK + 1) * 4);
    int* gcursor = (int*)alloc((size_t)NBUCK * 4);
    int2* part = (int2*)alloc((size_t)N_EDGES * 8);
    int2* sorted = (int2*)alloc((size_t)N_EDGES * 8);
    int* off = (int*)alloc((size_t)(N_NODES + 1) * 4);
    float* a = (float*)alloc((size_t)N_NODES * 4);
    float* b = (float*)alloc((size_t)N_NODES * 4);
    float* vrel = (float*)alloc(DIM * 4);
    float* vroot = (float*)alloc(DIM * 4);
    float* cb3 = (float*)alloc(4);

    hipMemsetAsync(zbase, 0, zbytes, stream);

    k_front<<<NB_HIST + NB_WCONV + 1, 256, 0, stream>>>(
        dst, W1rel, W1root, W3rel, W3root, b3, Wlin,
        wbh, wbl, ghist, ticket_hist, boff, gcursor, vrel, vroot, cb3);

    k_partition<<<NB_HIST, 256, 0, stream>>>(src, dst, ew, gcursor, part);

    k_gemm<<<dim3(NBUCK, 2), 256, 65536, stream>>>(x, wbh, wbl, b1, yb, r);

    k_bucketsort<<<NBUCK, 256, 0, stream>>>(boff, part, sorted, off);

    k_agg<<<(N_NODES + 3) / 4, 256, 0, stream>>>(
        (const unsigned int*)yb, (const float2*)r, off, sorted,
        (const float2*)vrel, (const float2*)vroot, a, b);

    k_reduce_final<<<RED_BLOCKS, 256, 0, stream>>>(
        sorted, off, a, b, batch, gpart, gpartc, ticket_red, cb3, blin, out);
}